// Round 20
// baseline (151.208 us; speedup 1.0000x reference)
//
#include <hip/hip_runtime.h>

#define MTOT (16 * 4096)   // 65536 queries
#define KDIM 256           // vector dim
#define CBSZ 1024          // codebook size

using half8  = _Float16 __attribute__((ext_vector_type(8)));
using f32x16 = float    __attribute__((ext_vector_type(16)));

// ---------------------------------------------------------------------------
// Kernel 1 (prep): codebook -> fragment-major fp16 hi/lo + squared norms.
// cbF layout (half8 units): [panel(32)][kc(16)][term(2)][lane(64)]
//   lane = g*32 + (c&31), holds cb[c][kc*16 + g*8 .. +8]
// ---------------------------------------------------------------------------
__global__ void vq_prep(const float* __restrict__ cb,
                        _Float16* __restrict__ cbF, float* __restrict__ hn) {
    const int flat = blockIdx.x * 256 + threadIdx.x;   // 32768 total
    const int c = flat >> 5;
    const int grp = flat & 31;
    const int kc = grp >> 1, g = grp & 1;
    const float* p = cb + (size_t)c * KDIM + grp * 8;
    float4 f0 = *reinterpret_cast<const float4*>(p);
    float4 f1 = *reinterpret_cast<const float4*>(p + 4);
    float fv[8] = {f0.x, f0.y, f0.z, f0.w, f1.x, f1.y, f1.z, f1.w};
    half8 h, l;
    float s = 0.0f;
    #pragma unroll
    for (int j = 0; j < 8; ++j) {
        h[j] = (_Float16)fv[j];
        l[j] = (_Float16)(fv[j] - (float)h[j]);
        s += fv[j] * fv[j];
    }
    const int pan = c >> 5, m = c & 31;
    const int lane = g * 32 + m;
    const size_t off = (((size_t)pan * 16 + kc) * 2 + 0) * 64 + lane;  // half8 units
    *reinterpret_cast<half8*>(cbF + off * 8) = h;
    *reinterpret_cast<half8*>(cbF + (off + 64) * 8) = l;               // term=1 (+64 half8)
    #pragma unroll
    for (int d = 16; d; d >>= 1) s += __shfl_xor(s, d);
    if (grp == 0) hn[c] = s;
}

// ---------------------------------------------------------------------------
// Kernel 2: MFMA distance GEMM + argmin + fused gather/loss.
// R20: OCCUPANCY restructure.  512 threads but 32 queries/block:
//   - qF = 32 KB  -> LDS no longer caps residency (3-4 blocks/CU possible)
//   - acc[1] = 16 AGPR; arch <=64 (LB(512,4)) -> <=80 regs/wave total
//     -> >=6 waves/SIMD guaranteed by the 512-reg unified pool (R12-R16
//     model), 8/SIMD if arch lands ~48.  1.5-2x today's latency hiding.
//   - serial acc chain is fine: >=6 waves x (1 MFMA/16cyc dep) saturates
//     the 1-per-8cyc matrix pipe from TLP alone.
// Per kc: 2 A-loads (L2) + 2 B-LDS-reads + 3 MFMAs in the EXACT R8-lineage
// order (Ah*bh, Al*bh, Ah*bl into one acc) -> numerics byte-identical.
// Cost: codebook read once per 32 queries -> 2 GB L2 (~25 TB/s, under the
// 34.5 ceiling).  Shell (staging/overlay/gather/loss) = validated R16/R18
// structure with sizes halved.  No setprio / prefetch / byte-punning.
// ---------------------------------------------------------------------------
__global__ __launch_bounds__(512, 4)
void vq_main(const float* __restrict__ A,          // z_e [MTOT][KDIM] fp32
             const _Float16* __restrict__ cbF,     // fragment-major codebook
             const float* __restrict__ hn,         // [CBSZ] norms
             const float* __restrict__ cb,         // original codebook fp32
             float* __restrict__ out_idx_f,
             float* __restrict__ zq,
             float* __restrict__ part_s,           // [2048] per-block bv sums
             float* __restrict__ part_x2) {        // [2048*8] per-wave x^2 sums
    // qF layout (half8 units): [kc(16)][term(2)][slot(64)]  (single qg)
    __shared__ _Float16 qF[16 * 2 * 64 * 8];       // 32 KB

    const int tid = threadIdx.x;
    const int qbase = blockIdx.x * 32;
    const int lane = tid & 63;
    const int wave = tid >> 6;

    // ---- stage queries: fp32 -> fp16 hi/lo fragments in LDS; accumulate x^2
    float xsq = 0.0f;
    #pragma unroll
    for (int it = 0; it < 2; ++it) {
        const int flat = it * 512 + tid;            // 1024 groups
        const int q = flat >> 5;                    // 0..31
        const int grp = flat & 31;
        const int kc = grp >> 1, g = grp & 1;
        const float* p = A + (size_t)(qbase + q) * KDIM + grp * 8;
        float4 f0 = *reinterpret_cast<const float4*>(p);
        float4 f1 = *reinterpret_cast<const float4*>(p + 4);
        float fv[8] = {f0.x, f0.y, f0.z, f0.w, f1.x, f1.y, f1.z, f1.w};
        half8 h, l;
        #pragma unroll
        for (int j = 0; j < 8; ++j) {
            h[j] = (_Float16)fv[j];
            l[j] = (_Float16)(fv[j] - (float)h[j]);
            xsq += fv[j] * fv[j];
        }
        const int lw = g * 32 + (q & 31);
        const int sl = lw ^ (kc & 7);               // swizzled 16B slot
        _Float16* dst = qF + ((kc * 2 + 0) * 64 + sl) * 8;
        *reinterpret_cast<half8*>(dst) = h;
        *reinterpret_cast<half8*>(dst + 512) = l;   // term=1: +64 half8 = +512 halves
    }
    #pragma unroll
    for (int d = 32; d; d >>= 1) xsq += __shfl_xor(xsq, d);
    if (lane == 0) part_x2[blockIdx.x * 8 + wave] = xsq;
    __syncthreads();

    const int m31 = lane & 31;
    const int g = lane >> 5;

    float minv0 = 3.4e38f;
    int   mini0 = 0;

    #pragma unroll 1
    for (int pi = 0; pi < 4; ++pi) {
        const int pan = wave * 4 + pi;              // one panel at a time

        f32x16 acc = (f32x16){};

        // A-fragment address helper (half8 units)
        #define AFRAG(kc_, t_) \
            (*reinterpret_cast<const half8*>(cbF + ((((size_t)pan * 16 + (kc_)) * 2 + (t_)) * 64 + lane) * 8))
        #define BPTR(kc_, sl_) (qF + (((kc_) * 2 + 0) * 64 + (sl_)) * 8)

        #pragma unroll 4
        for (int kc = 0; kc < 16; ++kc) {
            half8 Ah = AFRAG(kc, 0);
            half8 Al = AFRAG(kc, 1);
            const int sl = lane ^ (kc & 7);
            const _Float16* qb = BPTR(kc, sl);
            half8 bh = *reinterpret_cast<const half8*>(qb);
            half8 bl = *reinterpret_cast<const half8*>(qb + 512);

            // EXACT R8-lineage per-kc order: hh, lh, hl into one acc
            acc = __builtin_amdgcn_mfma_f32_32x32x16_f16(Ah, bh, acc, 0, 0, 0);
            acc = __builtin_amdgcn_mfma_f32_32x32x16_f16(Al, bh, acc, 0, 0, 0);
            acc = __builtin_amdgcn_mfma_f32_32x32x16_f16(Ah, bl, acc, 0, 0, 0);
        }
        #undef AFRAG
        #undef BPTR

        // epilogue: surrogate distance + running argmin (ascending codeword).
        const int cwb = pan * 32 + 4 * g;
        #pragma unroll
        for (int r = 0; r < 16; ++r) {
            const int cw = cwb + (r & 3) + 8 * (r >> 2);
            const float hc = hn[cw];
            float s = fmaf(-2.0f, acc[r], hc);
            if (s < minv0) { minv0 = s; mini0 = cw; }
        }
    }

    // combine the two g-halves in-register (tie -> lower index)
    {
        float ov = __shfl_xor(minv0, 32);
        int oi = __shfl_xor(mini0, 32);
        if (ov < minv0 || (ov == minv0 && oi < mini0)) { minv0 = ov; mini0 = oi; }
    }

    // qF is now dead -> overlay cross-wave scratch + final indices on it
    __syncthreads();
    float* sm   = reinterpret_cast<float*>(qF);          // [8][32]
    int*   si   = reinterpret_cast<int*>(qF) + 256;      // [8][32]
    int*   fidx = reinterpret_cast<int*>(qF) + 512;      // [32]
    if (g == 0) {
        sm[wave * 32 + m31] = minv0;
        si[wave * 32 + m31] = mini0;
    }
    __syncthreads();

    // cross-wave reduce (wave order = ascending codeword blocks), then
    // block loss partial = sum of selected surrogate distances.
    if (tid < 32) {
        float bv = sm[tid]; int bi = si[tid];
        #pragma unroll
        for (int w = 1; w < 8; ++w) {
            float v = sm[w * 32 + tid]; int ii = si[w * 32 + tid];
            if (v < bv || (v == bv && ii < bi)) { bv = v; bi = ii; }
        }
        out_idx_f[qbase + tid] = (float)bi;
        fidx[tid] = bi;
        float vs = bv;
        #pragma unroll
        for (int d = 16; d; d >>= 1) vs += __shfl_xor(vs, d);
        if (tid == 0) part_s[blockIdx.x] = vs;
    }
    __syncthreads();

    // fused gather: z_q rows for this block's 32 queries (coalesced, cb L2-hot)
    const float4* cb4 = reinterpret_cast<const float4*>(cb);
    float4* zq4 = reinterpret_cast<float4*>(zq) + (size_t)qbase * 64;
    #pragma unroll
    for (int it = 0; it < 4; ++it) {
        const int j = it * 512 + tid;               // 2048 float4 units
        const int q = j >> 6, seg = j & 63;
        const int cw = fidx[q];
        zq4[j] = cb4[(size_t)cw * 64 + seg];
    }
}

// ---------------------------------------------------------------------------
// Kernel 3: reduce partials -> loss = (sum_s + sum_x2) / (B*N*D)
// ---------------------------------------------------------------------------
__global__ void vq_finish(const float* __restrict__ part_s,
                          const float* __restrict__ part_x2,
                          float* __restrict__ out_loss) {
    float s = 0.0f;
    for (int i = threadIdx.x; i < 2048; i += 256) s += part_s[i];
    for (int i = threadIdx.x; i < 16384; i += 256) s += part_x2[i];
    #pragma unroll
    for (int d = 32; d; d >>= 1) s += __shfl_xor(s, d);
    __shared__ float ps[4];
    if ((threadIdx.x & 63) == 0) ps[threadIdx.x >> 6] = s;
    __syncthreads();
    if (threadIdx.x == 0)
        *out_loss = (ps[0] + ps[1] + ps[2] + ps[3]) * (1.0f / 16777216.0f);
}

extern "C" void kernel_launch(void* const* d_in, const int* in_sizes, int n_in,
                              void* d_out, int out_size, void* d_ws, size_t ws_size,
                              hipStream_t stream) {
    const float* z_e = (const float*)d_in[0];
    const float* cb  = (const float*)d_in[1];

    float* out   = (float*)d_out;
    float* zq    = out;
    float* oidx  = out + (size_t)MTOT * KDIM;
    float* oloss = out + (size_t)MTOT * KDIM + MTOT;

    char* ws = (char*)d_ws;
    _Float16* cbF  = (_Float16*)ws;                              // 1 MB
    float* hn      = (float*)(ws + 1024 * 1024);                 // 4 KB
    float* part_s  = (float*)(ws + 1024 * 1024 + 4096);          // 8 KB
    float* part_x2 = (float*)(ws + 1024 * 1024 + 4096 + 8192);   // 64 KB

    vq_prep<<<128, 256, 0, stream>>>(cb, cbF, hn);
    vq_main<<<MTOT / 32, 512, 0, stream>>>(z_e, cbF, hn, cb, oidx, zq,
                                           part_s, part_x2);
    vq_finish<<<1, 256, 0, stream>>>(part_s, part_x2, oloss);
}